// Round 6
// baseline (317.484 us; speedup 1.0000x reference)
//
#include <hip/hip_runtime.h>
#include <math.h>

#define BB 4
#define SS 2048
#define DD 1024
#define HH 16
#define DHH 64
#define NBH 64

typedef __attribute__((ext_vector_type(8))) short bf16x8;
typedef __attribute__((ext_vector_type(8))) unsigned short ushort8;
typedef __attribute__((ext_vector_type(4))) float f32x4;
typedef __attribute__((ext_vector_type(16))) float f32x16;
typedef unsigned short u16;

__device__ inline u16 f2bf(float x) {
    union { float f; unsigned u; } v; v.f = x;
    unsigned r = v.u + 0x7fffu + ((v.u >> 16) & 1u);   // RNE
    return (u16)(r >> 16);
}

__device__ inline void gload16(const u16* g, u16* l) {
    __builtin_amdgcn_global_load_lds(
        (const __attribute__((address_space(1))) unsigned int*)(const void*)g,
        (__attribute__((address_space(3))) unsigned int*)(void*)l, 16, 0, 0);
}

// ---------------------------------------------------------------------------
// fp32 -> bf16 conversion. Rows s >= ceil32(vlen[b]) of keys/values are
// skipped: never consumed unmasked downstream (stay 0xAA poison = tiny finite).
// ---------------------------------------------------------------------------
__global__ __launch_bounds__(256)
void cvt_qkv(const float* __restrict__ q, const float* __restrict__ k,
             const float* __restrict__ v, const int* __restrict__ vlens,
             u16* __restrict__ oq, u16* __restrict__ ok, u16* __restrict__ ov)
{
    const float* s; u16* d;
    if (blockIdx.y == 0) { s = q; d = oq; }
    else if (blockIdx.y == 1) { s = k; d = ok; }
    else { s = v; d = ov; }
    const size_t i0 = (size_t)blockIdx.x * 2048;
    if (blockIdx.y != 0) {
        const int b  = (int)(i0 >> 21);
        const int s0 = (int)(i0 >> 10) & (SS - 1);
        const int c32 = ((vlens[b] + 31) >> 5) << 5;
        if (s0 >= c32) return;
    }
    const size_t i = i0 + (size_t)threadIdx.x * 8;
    const float4 a = *(const float4*)(s + i);
    const float4 c = *(const float4*)(s + i + 4);
    ushort8 r;
    r[0] = f2bf(a.x); r[1] = f2bf(a.y); r[2] = f2bf(a.z); r[3] = f2bf(a.w);
    r[4] = f2bf(c.x); r[5] = f2bf(c.y); r[6] = f2bf(c.z); r[7] = f2bf(c.w);
    *(ushort8*)(d + i) = r;
}

__global__ __launch_bounds__(256)
void cvt_w(const float* __restrict__ a, const float* __restrict__ b,
           const float* __restrict__ c, const float* __restrict__ e,
           u16* __restrict__ oa, u16* __restrict__ ob,
           u16* __restrict__ oc, u16* __restrict__ oe)
{
    const float* s; u16* d;
    if (blockIdx.y == 0) { s = a; d = oa; }
    else if (blockIdx.y == 1) { s = b; d = ob; }
    else if (blockIdx.y == 2) { s = c; d = oc; }
    else { s = e; d = oe; }
    const size_t i = ((size_t)blockIdx.x * 256 + threadIdx.x) * 8;
    const float4 x = *(const float4*)(s + i);
    const float4 y = *(const float4*)(s + i + 4);
    ushort8 r;
    r[0] = f2bf(x.x); r[1] = f2bf(x.y); r[2] = f2bf(x.z); r[3] = f2bf(x.w);
    r[4] = f2bf(y.x); r[5] = f2bf(y.y); r[6] = f2bf(y.z); r[7] = f2bf(y.w);
    *(ushort8*)(d + i) = r;
}

// ---------------------------------------------------------------------------
// V (BH,S,DH) -> Vt (BH,DH,S) transpose, bf16, LDS tiled. Tiles wholly past
// ceil32(vlen[b]) skipped.
// ---------------------------------------------------------------------------
__global__ __launch_bounds__(256)
void transpose_v(const u16* __restrict__ Vp, const int* __restrict__ vlens,
                 u16* __restrict__ Vt)
{
    __shared__ __align__(16) u16 tile[64][72];
    const int t = threadIdx.x;
    const int s0 = blockIdx.x * 64;
    const int bh = blockIdx.y;
    const int b  = bh >> 4;
    const int c32 = ((vlens[b] + 31) >> 5) << 5;
    if (s0 >= c32) return;
    const u16* src = Vp + ((size_t)bh * SS + s0) * DHH;
    const int r = t >> 2, d0 = (t & 3) * 16;
    *(ushort8*)&tile[r][d0]     = *(const ushort8*)(src + r * DHH + d0);
    *(ushort8*)&tile[r][d0 + 8] = *(const ushort8*)(src + r * DHH + d0 + 8);
    __syncthreads();
    const int d = t >> 2, sl = (t & 3) * 16;
    ushort8 o0, o1;
    #pragma unroll
    for (int j = 0; j < 8; ++j) o0[j] = tile[sl + j][d];
    #pragma unroll
    for (int j = 0; j < 8; ++j) o1[j] = tile[sl + 8 + j][d];
    u16* dst = Vt + ((size_t)bh * DHH + d) * SS + s0 + sl;
    *(ushort8*)dst       = o0;
    *(ushort8*)(dst + 8) = o1;
}

// ---------------------------------------------------------------------------
// bf16 NT GEMM: C = A (Mx1024) @ B^T, 128x128 tile, BK=32, m97 structure.
// OUT_MODE 0: fp32 row-major. OUT_MODE 1: bf16 head-split (B,H,S,DH).
// SKIP 1: early-exit blocks whose rows all have s >= ceil32(vlen[b]) (K/V
// projections only — those rows are never read unmasked by flash).
// ---------------------------------------------------------------------------
template<int OUT_MODE, int SKIP>
__global__ __launch_bounds__(256)
void gemm_nt(const u16* __restrict__ A, const u16* __restrict__ B,
             void* __restrict__ Cv, const int* __restrict__ vlens)
{
    __shared__ __align__(16) u16 As[128 * 32];
    __shared__ __align__(16) u16 Bs[128 * 32];
    const int m0 = blockIdx.y * 128, n0 = blockIdx.x * 128;
    if (SKIP) {
        const int b = m0 >> 11, s0 = m0 & (SS - 1);
        const int c32 = ((vlens[b] + 31) >> 5) << 5;
        if (s0 >= c32) return;
    }
    const int t = threadIdx.x;
    const int w = t >> 6, l = t & 63;
    const int lm = l & 15, lg = l >> 4;
    const int wr = w >> 1, wc = w & 1;

    const u16* ga = A + (size_t)(m0 + w * 32 + (l >> 2)) * DD + (l & 3) * 8;
    const u16* gb = B + (size_t)(n0 + w * 32 + (l >> 2)) * DD + (l & 3) * 8;
    u16* lA0 = &As[w * 1024];
    u16* lA1 = &As[w * 1024 + 512];
    u16* lB0 = &Bs[w * 1024];
    u16* lB1 = &Bs[w * 1024 + 512];

    f32x4 acc[4][4];
    #pragma unroll
    for (int i = 0; i < 4; ++i)
        #pragma unroll
        for (int j = 0; j < 4; ++j)
            acc[i][j] = (f32x4){0.f, 0.f, 0.f, 0.f};

    for (int k0 = 0; k0 < DD; k0 += 32) {
        __syncthreads();
        gload16(ga + k0,           lA0);
        gload16(ga + k0 + 16 * DD, lA1);
        gload16(gb + k0,           lB0);
        gload16(gb + k0 + 16 * DD, lB1);
        __syncthreads();
        bf16x8 af[4], bfr[4];
        #pragma unroll
        for (int mi = 0; mi < 4; ++mi)
            af[mi] = *(const bf16x8*)&As[(wr * 64 + mi * 16 + lm) * 32 + lg * 8];
        #pragma unroll
        for (int ni = 0; ni < 4; ++ni)
            bfr[ni] = *(const bf16x8*)&Bs[(wc * 64 + ni * 16 + lm) * 32 + lg * 8];
        #pragma unroll
        for (int mi = 0; mi < 4; ++mi)
            #pragma unroll
            for (int ni = 0; ni < 4; ++ni)
                acc[mi][ni] = __builtin_amdgcn_mfma_f32_16x16x32_bf16(
                    af[mi], bfr[ni], acc[mi][ni], 0, 0, 0);
    }

    #pragma unroll
    for (int mi = 0; mi < 4; ++mi) {
        #pragma unroll
        for (int r = 0; r < 4; ++r) {
            const int m = m0 + wr * 64 + mi * 16 + lg * 4 + r;
            if (OUT_MODE == 0) {
                float* C = (float*)Cv;
                #pragma unroll
                for (int ni = 0; ni < 4; ++ni)
                    C[(size_t)m * DD + n0 + wc * 64 + ni * 16 + lm] = acc[mi][ni][r];
            } else {
                u16* C = (u16*)Cv;
                const int b = m >> 11, s = m & (SS - 1);
                #pragma unroll
                for (int ni = 0; ni < 4; ++ni) {
                    const int n = n0 + wc * 64 + ni * 16 + lm;
                    const int h = n >> 6, dh = n & 63;
                    C[(((size_t)b * HH + h) * SS + s) * DHH + dh] = f2bf(acc[mi][ni][r]);
                }
            }
        }
    }
}

// ---------------------------------------------------------------------------
// MFMA flash attention v5: 32x32x16 double-swapped (v4 math, verified) +
// KV-split x2 with in-block LDS combine.
//   wave w: pair = w>>1 (q-subtile), half = w&1 (KV range half)
//   half0: tiles [0, ntb2), half1: [ntb2, ntb)   (ntb2 = ceil(ntb/2) >= half1)
// half1 writes partial (o fp32, m, l) to LDS; barrier; half0 merges, writes AO.
// Grid = 2048 flat blocks (b in low bits -> batches interleaved in dispatch);
// 8192 waves = 8/SIMD launched, ~5-6 resident -> drain absorbed by refill.
// ---------------------------------------------------------------------------
#define LOADK4(coff) do {                                                      \
    const u16* kp_ = kb + (size_t)(coff) * DHH;                                \
    kf[0] = *(const bf16x8*)kp_;                                               \
    kf[1] = *(const bf16x8*)(kp_ + 16);                                        \
    kf[2] = *(const bf16x8*)(kp_ + 32);                                        \
    kf[3] = *(const bf16x8*)(kp_ + 48);                                        \
} while (0)

#define LOADV4(coff) do {                                                      \
    const u16* vp_ = vb + (coff);                                              \
    va[0] = *(const bf16x8*)vp_;                                               \
    va[1] = *(const bf16x8*)(vp_ + 16);                                        \
    va[2] = *(const bf16x8*)(vp_ + (size_t)32 * SS);                           \
    va[3] = *(const bf16x8*)(vp_ + (size_t)32 * SS + 16);                      \
} while (0)

__global__ __launch_bounds__(256)
void flash_mfma5(const u16* __restrict__ Qp, const u16* __restrict__ Kp,
                 const u16* __restrict__ Vt, const int* __restrict__ vlens,
                 u16* __restrict__ AO)
{
    __shared__ float olds[2][64][33];   // [pair][d][q], half1 partial O
    __shared__ float mst[2][2][32];     // [pair][{m,l}][q]
    const int t = threadIdx.x, w = t >> 6, l = t & 63;
    const int l31 = l & 31, hi = l >> 5;
    const int pair = w >> 1, half = w & 1;
    const int x = blockIdx.x;
    const int b = x & 3, h = (x >> 2) & 15, qblk = x >> 6;
    const int bh = b * 16 + h;
    const int q0 = qblk * 64 + pair * 32;
    const int vlen = vlens[b];
    const int ntb  = (vlen + 31) >> 5;
    const int ntb2 = (ntb + 1) >> 1;
    const int tb0 = half ? ntb2 : 0;
    const int tb1 = half ? ntb  : ntb2;

    const float SC = 0.18033688011112042f;   // 0.125 * log2(e)

    const u16* qb = Qp + ((size_t)bh * SS + q0 + l31) * DHH + hi * 8;
    bf16x8 qv[4];
    qv[0] = *(const bf16x8*)qb;
    qv[1] = *(const bf16x8*)(qb + 16);
    qv[2] = *(const bf16x8*)(qb + 32);
    qv[3] = *(const bf16x8*)(qb + 48);

    const u16* kb = Kp + ((size_t)bh * SS + l31) * DHH + hi * 8;
    const u16* vb = Vt + ((size_t)bh * DHH + l31) * SS + hi * 8;

    bf16x8 kf[4], va[4];
    f32x16 ot0, ot1;
    #pragma unroll
    for (int r = 0; r < 16; ++r) { ot0[r] = 0.f; ot1[r] = 0.f; }
    float m_run = -3e38f, l_run = 0.f;

    if (tb0 < tb1) { LOADK4(tb0 * 32); LOADV4(tb0 * 32); }

    for (int tt = tb0; tt < tb1; ++tt) {
        const int c0 = tt * 32;
        f32x16 z;
        #pragma unroll
        for (int r = 0; r < 16; ++r) z[r] = 0.f;
        __builtin_amdgcn_s_setprio(1);
        z = __builtin_amdgcn_mfma_f32_32x32x16_bf16(kf[0], qv[0], z, 0, 0, 0);
        z = __builtin_amdgcn_mfma_f32_32x32x16_bf16(kf[1], qv[1], z, 0, 0, 0);
        z = __builtin_amdgcn_mfma_f32_32x32x16_bf16(kf[2], qv[2], z, 0, 0, 0);
        z = __builtin_amdgcn_mfma_f32_32x32x16_bf16(kf[3], qv[3], z, 0, 0, 0);
        __builtin_amdgcn_s_setprio(0);
        if (tt + 1 < tb1) LOADK4(c0 + 32);

        if (vlen - c0 < 32) {
            #pragma unroll
            for (int r = 0; r < 16; ++r) {
                const int kvl = (r & 3) + 8 * (r >> 2) + 4 * hi;
                if (c0 + kvl >= vlen) z[r] = -3e38f;
            }
        }

        float mx = fmaxf(z[0], z[1]);
        #pragma unroll
        for (int r = 2; r < 16; ++r) mx = fmaxf(mx, z[r]);
        mx = fmaxf(mx, __shfl_xor(mx, 32));

        float corr = 1.f;
        if (!__all(mx <= m_run + 64.0f)) {
            const float mold = m_run;
            m_run = fmaxf(m_run, mx);
            corr = exp2f((mold - m_run) * SC);
            #pragma unroll
            for (int r = 0; r < 16; ++r) { ot0[r] *= corr; ot1[r] *= corr; }
        }

        const float msc = m_run * SC;
        float tsum = 0.f;
        #pragma unroll
        for (int r = 0; r < 16; ++r) {
            const float p = exp2f(__builtin_fmaf(z[r], SC, -msc));
            z[r] = p;
            tsum += p;
        }
        tsum += __shfl_xor(tsum, 32);
        l_run = l_run * corr + tsum;

        unsigned u0, u1, u2, u3, u4, u5, u6, u7;
        asm("v_cvt_pk_bf16_f32 %0, %1, %2" : "=v"(u0) : "v"(z[0]),  "v"(z[1]));
        asm("v_cvt_pk_bf16_f32 %0, %1, %2" : "=v"(u1) : "v"(z[2]),  "v"(z[3]));
        asm("v_cvt_pk_bf16_f32 %0, %1, %2" : "=v"(u2) : "v"(z[4]),  "v"(z[5]));
        asm("v_cvt_pk_bf16_f32 %0, %1, %2" : "=v"(u3) : "v"(z[6]),  "v"(z[7]));
        asm("v_cvt_pk_bf16_f32 %0, %1, %2" : "=v"(u4) : "v"(z[8]),  "v"(z[9]));
        asm("v_cvt_pk_bf16_f32 %0, %1, %2" : "=v"(u5) : "v"(z[10]), "v"(z[11]));
        asm("v_cvt_pk_bf16_f32 %0, %1, %2" : "=v"(u6) : "v"(z[12]), "v"(z[13]));
        asm("v_cvt_pk_bf16_f32 %0, %1, %2" : "=v"(u7) : "v"(z[14]), "v"(z[15]));

        const unsigned s0 = __shfl_xor(hi ? u0 : u2, 32);
        const unsigned s1 = __shfl_xor(hi ? u1 : u3, 32);
        const unsigned s2 = __shfl_xor(hi ? u4 : u6, 32);
        const unsigned s3 = __shfl_xor(hi ? u5 : u7, 32);

        unsigned f0w[4], f1w[4];
        f0w[0] = hi ? s0 : u0;  f0w[1] = hi ? s1 : u1;
        f0w[2] = hi ? u2 : s0;  f0w[3] = hi ? u3 : s1;
        f1w[0] = hi ? s2 : u4;  f1w[1] = hi ? s3 : u5;
        f1w[2] = hi ? u6 : s2;  f1w[3] = hi ? u7 : s3;
        bf16x8 pb0, pb1;
        #pragma unroll
        for (int i = 0; i < 4; ++i) {
            ((unsigned*)&pb0)[i] = f0w[i];
            ((unsigned*)&pb1)[i] = f1w[i];
        }

        __builtin_amdgcn_s_setprio(1);
        ot0 = __builtin_amdgcn_mfma_f32_32x32x16_bf16(va[0], pb0, ot0, 0, 0, 0);
        ot0 = __builtin_amdgcn_mfma_f32_32x32x16_bf16(va[1], pb1, ot0, 0, 0, 0);
        ot1 = __builtin_amdgcn_mfma_f32_32x32x16_bf16(va[2], pb0, ot1, 0, 0, 0);
        ot1 = __builtin_amdgcn_mfma_f32_32x32x16_bf16(va[3], pb1, ot1, 0, 0, 0);
        __builtin_amdgcn_s_setprio(0);
        if (tt + 1 < tb1) LOADV4(c0 + 32);
    }

    // --- combine halves through LDS
    if (half) {
        #pragma unroll
        for (int r = 0; r < 16; ++r) {
            const int d = (r & 3) + 8 * (r >> 2) + 4 * hi;
            olds[pair][d][l31]      = ot0[r];
            olds[pair][d + 32][l31] = ot1[r];
        }
        if (hi == 0) {
            mst[pair][0][l31] = m_run;
            mst[pair][1][l31] = l_run;
        }
    }
    __syncthreads();
    if (!half) {
        const float m1 = mst[pair][0][l31];
        const float l1 = mst[pair][1][l31];
        const float M  = fmaxf(m_run, m1);
        const float a0 = exp2f((m_run - M) * SC);
        const float a1 = exp2f((m1 - M) * SC);
        const float inv = 1.f / (a0 * l_run + a1 * l1);
        u16* ob = AO + ((size_t)b * SS + q0 + l31) * DD + h * DHH + hi * 4;
        #pragma unroll
        for (int rq = 0; rq < 4; ++rq) {
            #pragma unroll
            for (int rp = 0; rp < 2; ++rp) {
                const int r  = rq * 4 + rp * 2;
                const int d0 = (r & 3) + 8 * (r >> 2) + 4 * hi;        // reg r
                const int d1 = ((r + 1) & 3) + 8 * ((r + 1) >> 2) + 4 * hi;
                const float v00 = (a0 * ot0[r]     + a1 * olds[pair][d0][l31]) * inv;
                const float v01 = (a0 * ot0[r + 1] + a1 * olds[pair][d1][l31]) * inv;
                const float v10 = (a0 * ot1[r]     + a1 * olds[pair][d0 + 32][l31]) * inv;
                const float v11 = (a0 * ot1[r + 1] + a1 * olds[pair][d1 + 32][l31]) * inv;
                unsigned w0, w1;
                asm("v_cvt_pk_bf16_f32 %0, %1, %2" : "=v"(w0) : "v"(v00), "v"(v01));
                asm("v_cvt_pk_bf16_f32 %0, %1, %2" : "=v"(w1) : "v"(v10), "v"(v11));
                *(unsigned*)(ob + rq * 8 + rp * 2)      = w0;
                *(unsigned*)(ob + 32 + rq * 8 + rp * 2) = w1;
            }
        }
    }
}

extern "C" void kernel_launch(void* const* d_in, const int* in_sizes, int n_in,
                              void* d_out, int out_size, void* d_ws, size_t ws_size,
                              hipStream_t stream) {
    const float* queries = (const float*)d_in[0];
    const float* keys    = (const float*)d_in[1];
    const float* values  = (const float*)d_in[2];
    const int*   vlens   = (const int*)d_in[3];
    const float* Wq      = (const float*)d_in[4];
    const float* Wk      = (const float*)d_in[5];
    const float* Wv      = (const float*)d_in[6];
    const float* Wo      = (const float*)d_in[7];

    u16* ws = (u16*)d_ws;
    const size_t NX = (size_t)BB * SS * DD;   // 8,388,608
    const size_t NW = (size_t)DD * DD;        // 1,048,576
    u16* Xq  = ws;
    u16* Xk  = Xq  + NX;
    u16* Xv  = Xk  + NX;
    u16* Wqb = Xv  + NX;
    u16* Wkb = Wqb + NW;
    u16* Wvb = Wkb + NW;
    u16* Wob = Wvb + NW;
    u16* Qp  = Wob + NW;
    u16* Kp  = Qp  + NX;
    u16* Vp  = Kp  + NX;
    u16* Vtb = Vp  + NX;
    u16* AO  = Xq;   // alias: Xq dead after the Q projection

    cvt_qkv<<<dim3(NX / 2048, 3), 256, 0, stream>>>(queries, keys, values, vlens,
                                                    Xq, Xk, Xv);
    cvt_w<<<dim3(NW / 2048, 4), 256, 0, stream>>>(Wq, Wk, Wv, Wo, Wqb, Wkb, Wvb, Wob);

    const dim3 gg(DD / 128, (BB * SS) / 128);   // (8, 64)
    gemm_nt<1, 0><<<gg, 256, 0, stream>>>(Xq, Wqb, Qp, nullptr);
    gemm_nt<1, 1><<<gg, 256, 0, stream>>>(Xk, Wkb, Kp, vlens);
    gemm_nt<1, 1><<<gg, 256, 0, stream>>>(Xv, Wvb, Vp, vlens);

    transpose_v<<<dim3(SS / 64, NBH), 256, 0, stream>>>(Vp, vlens, Vtb);
    flash_mfma5<<<dim3(2048), 256, 0, stream>>>(Qp, Kp, Vtb, vlens, AO);

    gemm_nt<0, 0><<<gg, 256, 0, stream>>>(AO, Wob, (float*)d_out, nullptr);
}

// Round 8
// 298.451 us; speedup vs baseline: 1.0638x; 1.0638x over previous
//
#include <hip/hip_runtime.h>
#include <math.h>

#define BB 4
#define SS 2048
#define DD 1024
#define HH 16
#define DHH 64
#define NBH 64

typedef __attribute__((ext_vector_type(8))) short bf16x8;
typedef __attribute__((ext_vector_type(8))) unsigned short ushort8;
typedef __attribute__((ext_vector_type(4))) float f32x4;
typedef __attribute__((ext_vector_type(16))) float f32x16;
typedef __attribute__((ext_vector_type(2))) unsigned u32x2;
typedef unsigned short u16;

__device__ inline u16 f2bf(float x) {
    union { float f; unsigned u; } v; v.f = x;
    unsigned r = v.u + 0x7fffu + ((v.u >> 16) & 1u);   // RNE
    return (u16)(r >> 16);
}

__device__ inline void gload16(const u16* g, u16* l) {
    __builtin_amdgcn_global_load_lds(
        (const __attribute__((address_space(1))) unsigned int*)(const void*)g,
        (__attribute__((address_space(3))) unsigned int*)(void*)l, 16, 0, 0);
}

// SSA-safe cross-half primitives (no register-aliasing hazard: the builtin
// returns BOTH results as a value pair).
__device__ inline void plswap(unsigned& a, unsigned& b) {
    u32x2 r = __builtin_amdgcn_permlane32_swap(a, b, false, false);
    a = r[0]; b = r[1];
}
__device__ inline float xhalf_max(float x) {
    u32x2 r = __builtin_amdgcn_permlane32_swap(
        __float_as_uint(x), __float_as_uint(x), false, false);
    return fmaxf(__uint_as_float(r[0]), __uint_as_float(r[1]));
}
__device__ inline float xhalf_sum(float x) {
    u32x2 r = __builtin_amdgcn_permlane32_swap(
        __float_as_uint(x), __float_as_uint(x), false, false);
    return __uint_as_float(r[0]) + __uint_as_float(r[1]);
}

// ---------------------------------------------------------------------------
// fp32 -> bf16 conversion, ALL tensors in one launch.
// blocks [0,12288): q/k/v (4096 each); [12288,14336): weights (512 each).
// K/V rows s >= ceil32(vlen[b]) skipped (never consumed unmasked downstream).
// ---------------------------------------------------------------------------
__global__ __launch_bounds__(256)
void cvt_all(const float* __restrict__ q, const float* __restrict__ k,
             const float* __restrict__ v,
             const float* __restrict__ wq, const float* __restrict__ wk,
             const float* __restrict__ wv, const float* __restrict__ wo,
             const int* __restrict__ vlens,
             u16* __restrict__ oq, u16* __restrict__ ok, u16* __restrict__ ov,
             u16* __restrict__ owq, u16* __restrict__ owk,
             u16* __restrict__ owv, u16* __restrict__ owo)
{
    const int id = blockIdx.x;
    const float* s; u16* d; size_t i0;
    if (id < 12288) {
        const int y = id >> 12, xx = id & 4095;
        i0 = (size_t)xx * 2048;
        if (y == 0) { s = q; d = oq; }
        else if (y == 1) { s = k; d = ok; }
        else { s = v; d = ov; }
        if (y != 0) {
            const int b  = (int)(i0 >> 21);
            const int s0 = (int)(i0 >> 10) & (SS - 1);
            const int c32 = ((vlens[b] + 31) >> 5) << 5;
            if (s0 >= c32) return;
        }
    } else {
        const int r = id - 12288;
        const int y = r >> 9, xx = r & 511;
        i0 = (size_t)xx * 2048;
        if (y == 0) { s = wq; d = owq; }
        else if (y == 1) { s = wk; d = owk; }
        else if (y == 2) { s = wv; d = owv; }
        else { s = wo; d = owo; }
    }
    const size_t i = i0 + (size_t)threadIdx.x * 8;
    const float4 a = *(const float4*)(s + i);
    const float4 c = *(const float4*)(s + i + 4);
    ushort8 r;
    r[0] = f2bf(a.x); r[1] = f2bf(a.y); r[2] = f2bf(a.z); r[3] = f2bf(a.w);
    r[4] = f2bf(c.x); r[5] = f2bf(c.y); r[6] = f2bf(c.z); r[7] = f2bf(c.w);
    *(ushort8*)(d + i) = r;
}

// ---------------------------------------------------------------------------
// V (BH,S,DH) -> Vt (BH,DH,S) transpose, bf16, LDS tiled. Tiles wholly past
// ceil32(vlen[b]) skipped.
// ---------------------------------------------------------------------------
__global__ __launch_bounds__(256)
void transpose_v(const u16* __restrict__ Vp, const int* __restrict__ vlens,
                 u16* __restrict__ Vt)
{
    __shared__ __align__(16) u16 tile[64][72];
    const int t = threadIdx.x;
    const int s0 = blockIdx.x * 64;
    const int bh = blockIdx.y;
    const int b  = bh >> 4;
    const int c32 = ((vlens[b] + 31) >> 5) << 5;
    if (s0 >= c32) return;
    const u16* src = Vp + ((size_t)bh * SS + s0) * DHH;
    const int r = t >> 2, d0 = (t & 3) * 16;
    *(ushort8*)&tile[r][d0]     = *(const ushort8*)(src + r * DHH + d0);
    *(ushort8*)&tile[r][d0 + 8] = *(const ushort8*)(src + r * DHH + d0 + 8);
    __syncthreads();
    const int d = t >> 2, sl = (t & 3) * 16;
    ushort8 o0, o1;
    #pragma unroll
    for (int j = 0; j < 8; ++j) o0[j] = tile[sl + j][d];
    #pragma unroll
    for (int j = 0; j < 8; ++j) o1[j] = tile[sl + 8 + j][d];
    u16* dst = Vt + ((size_t)bh * DHH + d) * SS + s0 + sl;
    *(ushort8*)dst       = o0;
    *(ushort8*)(dst + 8) = o1;
}

// ---------------------------------------------------------------------------
// Shared GEMM core: C = A (Mx1024) @ B^T, 128x128 tile, BK=32, m97 structure.
// OUT_MODE 0: fp32 row-major. OUT_MODE 1: bf16 head-split (B,H,S,DH).
// ---------------------------------------------------------------------------
template<int OUT_MODE>
__device__ __forceinline__
void gemm_core(const u16* __restrict__ A, const u16* __restrict__ B,
               void* __restrict__ Cv, int m0, int n0, u16* As, u16* Bs)
{
    const int t = threadIdx.x;
    const int w = t >> 6, l = t & 63;
    const int lm = l & 15, lg = l >> 4;
    const int wr = w >> 1, wc = w & 1;

    const u16* ga = A + (size_t)(m0 + w * 32 + (l >> 2)) * DD + (l & 3) * 8;
    const u16* gb = B + (size_t)(n0 + w * 32 + (l >> 2)) * DD + (l & 3) * 8;
    u16* lA0 = &As[w * 1024];
    u16* lA1 = &As[w * 1024 + 512];
    u16* lB0 = &Bs[w * 1024];
    u16* lB1 = &Bs[w * 1024 + 512];

    f32x4 acc[4][4];
    #pragma unroll
    for (int i = 0; i < 4; ++i)
        #pragma unroll
        for (int j = 0; j < 4; ++j)
            acc[i][j] = (f32x4){0.f, 0.f, 0.f, 0.f};

    for (int k0 = 0; k0 < DD; k0 += 32) {
        __syncthreads();
        gload16(ga + k0,           lA0);
        gload16(ga + k0 + 16 * DD, lA1);
        gload16(gb + k0,           lB0);
        gload16(gb + k0 + 16 * DD, lB1);
        __syncthreads();
        bf16x8 af[4], bfr[4];
        #pragma unroll
        for (int mi = 0; mi < 4; ++mi)
            af[mi] = *(const bf16x8*)&As[(wr * 64 + mi * 16 + lm) * 32 + lg * 8];
        #pragma unroll
        for (int ni = 0; ni < 4; ++ni)
            bfr[ni] = *(const bf16x8*)&Bs[(wc * 64 + ni * 16 + lm) * 32 + lg * 8];
        #pragma unroll
        for (int mi = 0; mi < 4; ++mi)
            #pragma unroll
            for (int ni = 0; ni < 4; ++ni)
                acc[mi][ni] = __builtin_amdgcn_mfma_f32_16x16x32_bf16(
                    af[mi], bfr[ni], acc[mi][ni], 0, 0, 0);
    }

    #pragma unroll
    for (int mi = 0; mi < 4; ++mi) {
        #pragma unroll
        for (int r = 0; r < 4; ++r) {
            const int m = m0 + wr * 64 + mi * 16 + lg * 4 + r;
            if (OUT_MODE == 0) {
                float* C = (float*)Cv;
                #pragma unroll
                for (int ni = 0; ni < 4; ++ni)
                    C[(size_t)m * DD + n0 + wc * 64 + ni * 16 + lm] = acc[mi][ni][r];
            } else {
                u16* C = (u16*)Cv;
                const int b = m >> 11, s = m & (SS - 1);
                #pragma unroll
                for (int ni = 0; ni < 4; ++ni) {
                    const int n = n0 + wc * 64 + ni * 16 + lm;
                    const int h = n >> 6, dh = n & 63;
                    C[(((size_t)b * HH + h) * SS + s) * DHH + dh] = f2bf(acc[mi][ni][r]);
                }
            }
        }
    }
}

// All 3 projections in one launch: z = 0/1/2 -> Q/K/V. K/V blocks wholly past
// ceil32(vlen[b]) early-exit (rows never read unmasked by flash).
__global__ __launch_bounds__(256)
void gemm_qkv(const u16* __restrict__ Xq, const u16* __restrict__ Xk,
              const u16* __restrict__ Xv,
              const u16* __restrict__ Wqb, const u16* __restrict__ Wkb,
              const u16* __restrict__ Wvb,
              u16* __restrict__ Qo, u16* __restrict__ Ko, u16* __restrict__ Vo,
              const int* __restrict__ vlens)
{
    __shared__ __align__(16) u16 As[128 * 32];
    __shared__ __align__(16) u16 Bs[128 * 32];
    const int z = blockIdx.z;
    const int m0 = blockIdx.y * 128, n0 = blockIdx.x * 128;
    const u16* A; const u16* B; u16* C;
    if (z == 0) { A = Xq; B = Wqb; C = Qo; }
    else if (z == 1) { A = Xk; B = Wkb; C = Ko; }
    else { A = Xv; B = Wvb; C = Vo; }
    if (z != 0) {
        const int b = m0 >> 11, s0 = m0 & (SS - 1);
        const int c32 = ((vlens[b] + 31) >> 5) << 5;
        if (s0 >= c32) return;
    }
    gemm_core<1>(A, B, (void*)C, m0, n0, As, Bs);
}

__global__ __launch_bounds__(256)
void gemm_out(const u16* __restrict__ A, const u16* __restrict__ B,
              float* __restrict__ C)
{
    __shared__ __align__(16) u16 As[128 * 32];
    __shared__ __align__(16) u16 Bs[128 * 32];
    gemm_core<0>(A, B, (void*)C, blockIdx.y * 128, blockIdx.x * 128, As, Bs);
}

// ---------------------------------------------------------------------------
// MFMA flash attention v6b = v4 structure (proven 142us) + SSA-safe
// permlane32_swap (builtin form — round-7's inline-asm reductions aliased
// both operands to one VGPR and broke m/l).
//   S^T = mfma(A=K, B=Q)     -> lane owns one q-row (q = lane&31) of scores
//   O^T = mfma(A=V^T, B=P^T) -> lane owns one q-row of output
// Flat batch-interleaved grid (b in low bits) smooths the vlen drain.
// ---------------------------------------------------------------------------
#define LOADK4(coff) do {                                                      \
    const u16* kp_ = kb + (size_t)(coff) * DHH;                                \
    kf[0] = *(const bf16x8*)kp_;                                               \
    kf[1] = *(const bf16x8*)(kp_ + 16);                                        \
    kf[2] = *(const bf16x8*)(kp_ + 32);                                        \
    kf[3] = *(const bf16x8*)(kp_ + 48);                                        \
} while (0)

#define LOADV4(coff) do {                                                      \
    const u16* vp_ = vb + (coff);                                              \
    va[0] = *(const bf16x8*)vp_;                                               \
    va[1] = *(const bf16x8*)(vp_ + 16);                                        \
    va[2] = *(const bf16x8*)(vp_ + (size_t)32 * SS);                           \
    va[3] = *(const bf16x8*)(vp_ + (size_t)32 * SS + 16);                      \
} while (0)

__global__ __launch_bounds__(256)
void flash_mfma6(const u16* __restrict__ Qp, const u16* __restrict__ Kp,
                 const u16* __restrict__ Vt, const int* __restrict__ vlens,
                 u16* __restrict__ AO)
{
    const int t = threadIdx.x, w = t >> 6, l = t & 63;
    const int l31 = l & 31, hi = l >> 5;
    const int x = blockIdx.x;
    const int b = x & 3, h = (x >> 2) & 15, qblk = x >> 6;   // 0..15
    const int bh = b * 16 + h;
    const int q0 = (qblk * 4 + w) * 32;
    const int vlen = vlens[b];
    const int ntb = (vlen + 31) >> 5;

    const float SC = 0.18033688011112042f;   // 0.125 * log2(e)

    const u16* qb = Qp + ((size_t)bh * SS + q0 + l31) * DHH + hi * 8;
    bf16x8 qv[4];
    qv[0] = *(const bf16x8*)qb;
    qv[1] = *(const bf16x8*)(qb + 16);
    qv[2] = *(const bf16x8*)(qb + 32);
    qv[3] = *(const bf16x8*)(qb + 48);

    const u16* kb = Kp + ((size_t)bh * SS + l31) * DHH + hi * 8;
    const u16* vb = Vt + ((size_t)bh * DHH + l31) * SS + hi * 8;

    bf16x8 kf[4], va[4];
    LOADK4(0);
    LOADV4(0);

    f32x16 ot0, ot1;
    #pragma unroll
    for (int r = 0; r < 16; ++r) { ot0[r] = 0.f; ot1[r] = 0.f; }
    float m_run = -3e38f, l_run = 0.f;

    for (int tt = 0; tt < ntb; ++tt) {
        const int c0 = tt * 32;
        f32x16 z;
        #pragma unroll
        for (int r = 0; r < 16; ++r) z[r] = 0.f;
        __builtin_amdgcn_s_setprio(1);
        z = __builtin_amdgcn_mfma_f32_32x32x16_bf16(kf[0], qv[0], z, 0, 0, 0);
        z = __builtin_amdgcn_mfma_f32_32x32x16_bf16(kf[1], qv[1], z, 0, 0, 0);
        z = __builtin_amdgcn_mfma_f32_32x32x16_bf16(kf[2], qv[2], z, 0, 0, 0);
        z = __builtin_amdgcn_mfma_f32_32x32x16_bf16(kf[3], qv[3], z, 0, 0, 0);
        __builtin_amdgcn_s_setprio(0);
        if (tt + 1 < ntb) LOADK4(c0 + 32);

        if (vlen - c0 < 32) {
            #pragma unroll
            for (int r = 0; r < 16; ++r) {
                const int kvl = (r & 3) + 8 * (r >> 2) + 4 * hi;
                if (c0 + kvl >= vlen) z[r] = -3e38f;
            }
        }

        // --- row max: 15 in-lane fmax + SSA-safe cross-half max
        float mx = fmaxf(z[0], z[1]);
        #pragma unroll
        for (int r = 2; r < 16; ++r) mx = fmaxf(mx, z[r]);
        mx = xhalf_max(mx);

        // --- defer-max: rescale only when raw max grows by > 64 (= 8 nats)
        float corr = 1.f;
        if (!__all(mx <= m_run + 64.0f)) {
            const float mold = m_run;
            m_run = fmaxf(m_run, mx);
            corr = exp2f((mold - m_run) * SC);
            #pragma unroll
            for (int r = 0; r < 16; ++r) { ot0[r] *= corr; ot1[r] *= corr; }
        }

        // --- p = exp2(z*SC - m*SC); in-lane sum + SSA-safe cross-half sum
        const float msc = m_run * SC;
        float tsum = 0.f;
        #pragma unroll
        for (int r = 0; r < 16; ++r) {
            const float p = exp2f(__builtin_fmaf(z[r], SC, -msc));
            z[r] = p;
            tsum += p;
        }
        tsum = xhalf_sum(tsum);
        l_run = l_run * corr + tsum;

        // --- pack P to bf16 pairs
        unsigned u0, u1, u2, u3, u4, u5, u6, u7;
        asm("v_cvt_pk_bf16_f32 %0, %1, %2" : "=v"(u0) : "v"(z[0]),  "v"(z[1]));
        asm("v_cvt_pk_bf16_f32 %0, %1, %2" : "=v"(u1) : "v"(z[2]),  "v"(z[3]));
        asm("v_cvt_pk_bf16_f32 %0, %1, %2" : "=v"(u2) : "v"(z[4]),  "v"(z[5]));
        asm("v_cvt_pk_bf16_f32 %0, %1, %2" : "=v"(u3) : "v"(z[6]),  "v"(z[7]));
        asm("v_cvt_pk_bf16_f32 %0, %1, %2" : "=v"(u4) : "v"(z[8]),  "v"(z[9]));
        asm("v_cvt_pk_bf16_f32 %0, %1, %2" : "=v"(u5) : "v"(z[10]), "v"(z[11]));
        asm("v_cvt_pk_bf16_f32 %0, %1, %2" : "=v"(u6) : "v"(z[12]), "v"(z[13]));
        asm("v_cvt_pk_bf16_f32 %0, %1, %2" : "=v"(u7) : "v"(z[14]), "v"(z[15]));

        // --- cross-half exchange, one permlane32_swap per word pair:
        // after swap u0 = {u0.lo-half ; u2.lo-half}, u2 = {u0.hi ; u2.hi}
        plswap(u0, u2);
        plswap(u1, u3);
        plswap(u4, u6);
        plswap(u5, u7);

        bf16x8 pb0, pb1;
        ((unsigned*)&pb0)[0] = u0; ((unsigned*)&pb0)[1] = u1;
        ((unsigned*)&pb0)[2] = u2; ((unsigned*)&pb0)[3] = u3;
        ((unsigned*)&pb1)[0] = u4; ((unsigned*)&pb1)[1] = u5;
        ((unsigned*)&pb1)[2] = u6; ((unsigned*)&pb1)[3] = u7;

        __builtin_amdgcn_s_setprio(1);
        ot0 = __builtin_amdgcn_mfma_f32_32x32x16_bf16(va[0], pb0, ot0, 0, 0, 0);
        ot0 = __builtin_amdgcn_mfma_f32_32x32x16_bf16(va[1], pb1, ot0, 0, 0, 0);
        ot1 = __builtin_amdgcn_mfma_f32_32x32x16_bf16(va[2], pb0, ot1, 0, 0, 0);
        ot1 = __builtin_amdgcn_mfma_f32_32x32x16_bf16(va[3], pb1, ot1, 0, 0, 0);
        __builtin_amdgcn_s_setprio(0);
        if (tt + 1 < ntb) LOADV4(c0 + 32);
    }

    // --- normalize + write: lane owns q-row q0+l31; d = 32*dh + (r&3)+8(r>>2)+4hi
    const float inv = 1.f / l_run;
    u16* ob = AO + ((size_t)b * SS + q0 + l31) * DD + h * DHH + hi * 4;
    #pragma unroll
    for (int rq = 0; rq < 4; ++rq) {
        #pragma unroll
        for (int rp = 0; rp < 2; ++rp) {
            const int r = rq * 4 + rp * 2;
            unsigned w0, w1;
            asm("v_cvt_pk_bf16_f32 %0, %1, %2" : "=v"(w0)
                : "v"(ot0[r] * inv), "v"(ot0[r + 1] * inv));
            asm("v_cvt_pk_bf16_f32 %0, %1, %2" : "=v"(w1)
                : "v"(ot1[r] * inv), "v"(ot1[r + 1] * inv));
            *(unsigned*)(ob + rq * 8 + rp * 2)      = w0;
            *(unsigned*)(ob + 32 + rq * 8 + rp * 2) = w1;
        }
    }
}

extern "C" void kernel_launch(void* const* d_in, const int* in_sizes, int n_in,
                              void* d_out, int out_size, void* d_ws, size_t ws_size,
                              hipStream_t stream) {
    const float* queries = (const float*)d_in[0];
    const float* keys    = (const float*)d_in[1];
    const float* values  = (const float*)d_in[2];
    const int*   vlens   = (const int*)d_in[3];
    const float* Wq      = (const float*)d_in[4];
    const float* Wk      = (const float*)d_in[5];
    const float* Wv      = (const float*)d_in[6];
    const float* Wo      = (const float*)d_in[7];

    u16* ws = (u16*)d_ws;
    const size_t NX = (size_t)BB * SS * DD;   // 8,388,608
    const size_t NW = (size_t)DD * DD;        // 1,048,576
    u16* Xq  = ws;
    u16* Xk  = Xq  + NX;
    u16* Xv  = Xk  + NX;
    u16* Wqb = Xv  + NX;
    u16* Wkb = Wqb + NW;
    u16* Wvb = Wkb + NW;
    u16* Wob = Wvb + NW;
    u16* Qp  = Wob + NW;
    u16* Kp  = Qp  + NX;
    u16* Vp  = Kp  + NX;
    u16* Vtb = Vp  + NX;
    u16* AO  = Xq;   // alias: Xq dead after the Q projection

    cvt_all<<<dim3(14336), 256, 0, stream>>>(queries, keys, values,
                                             Wq, Wk, Wv, Wo, vlens,
                                             Xq, Xk, Xv, Wqb, Wkb, Wvb, Wob);

    gemm_qkv<<<dim3(DD / 128, (BB * SS) / 128, 3), 256, 0, stream>>>(
        Xq, Xk, Xv, Wqb, Wkb, Wvb, Qp, Kp, Vp, vlens);

    transpose_v<<<dim3(SS / 64, NBH), 256, 0, stream>>>(Vp, vlens, Vtb);
    flash_mfma6<<<dim3(1024), 256, 0, stream>>>(Qp, Kp, Vtb, vlens, AO);

    gemm_out<<<dim3(DD / 128, (BB * SS) / 128), 256, 0, stream>>>(AO, Wob, (float*)d_out);
}

// Round 9
// 282.033 us; speedup vs baseline: 1.1257x; 1.0582x over previous
//
#include <hip/hip_runtime.h>
#include <math.h>

#define BB 4
#define SS 2048
#define DD 1024
#define HH 16
#define DHH 64
#define NBH 64

typedef __attribute__((ext_vector_type(8))) short bf16x8;
typedef __attribute__((ext_vector_type(8))) unsigned short ushort8;
typedef __attribute__((ext_vector_type(4))) float f32x4;
typedef __attribute__((ext_vector_type(16))) float f32x16;
typedef __attribute__((ext_vector_type(2))) unsigned u32x2;
typedef unsigned short u16;

__device__ inline u16 f2bf(float x) {
    union { float f; unsigned u; } v; v.f = x;
    unsigned r = v.u + 0x7fffu + ((v.u >> 16) & 1u);   // RNE
    return (u16)(r >> 16);
}

__device__ inline void gload16(const u16* g, u16* l) {
    __builtin_amdgcn_global_load_lds(
        (const __attribute__((address_space(1))) unsigned int*)(const void*)g,
        (__attribute__((address_space(3))) unsigned int*)(void*)l, 16, 0, 0);
}

// SSA-safe cross-half primitives (builtin returns BOTH results — no aliasing).
__device__ inline void plswap(unsigned& a, unsigned& b) {
    u32x2 r = __builtin_amdgcn_permlane32_swap(a, b, false, false);
    a = r[0]; b = r[1];
}
__device__ inline float xhalf_max(float x) {
    u32x2 r = __builtin_amdgcn_permlane32_swap(
        __float_as_uint(x), __float_as_uint(x), false, false);
    return fmaxf(__uint_as_float(r[0]), __uint_as_float(r[1]));
}
__device__ inline float xhalf_sum(float x) {
    u32x2 r = __builtin_amdgcn_permlane32_swap(
        __float_as_uint(x), __float_as_uint(x), false, false);
    return __uint_as_float(r[0]) + __uint_as_float(r[1]);
}

// ---------------------------------------------------------------------------
// fp32 -> bf16 conversion, ALL tensors in one launch.
// blocks [0,12288): q/k/v (4096 each); [12288,14336): weights (512 each).
// K/V rows s >= ceil32(vlen[b]) skipped (never consumed unmasked downstream).
// ---------------------------------------------------------------------------
__global__ __launch_bounds__(256)
void cvt_all(const float* __restrict__ q, const float* __restrict__ k,
             const float* __restrict__ v,
             const float* __restrict__ wq, const float* __restrict__ wk,
             const float* __restrict__ wv, const float* __restrict__ wo,
             const int* __restrict__ vlens,
             u16* __restrict__ oq, u16* __restrict__ ok, u16* __restrict__ ov,
             u16* __restrict__ owq, u16* __restrict__ owk,
             u16* __restrict__ owv, u16* __restrict__ owo)
{
    const int id = blockIdx.x;
    const float* s; u16* d; size_t i0;
    if (id < 12288) {
        const int y = id >> 12, xx = id & 4095;
        i0 = (size_t)xx * 2048;
        if (y == 0) { s = q; d = oq; }
        else if (y == 1) { s = k; d = ok; }
        else { s = v; d = ov; }
        if (y != 0) {
            const int b  = (int)(i0 >> 21);
            const int s0 = (int)(i0 >> 10) & (SS - 1);
            const int c32 = ((vlens[b] + 31) >> 5) << 5;
            if (s0 >= c32) return;
        }
    } else {
        const int r = id - 12288;
        const int y = r >> 9, xx = r & 511;
        i0 = (size_t)xx * 2048;
        if (y == 0) { s = wq; d = owq; }
        else if (y == 1) { s = wk; d = owk; }
        else if (y == 2) { s = wv; d = owv; }
        else { s = wo; d = owo; }
    }
    const size_t i = i0 + (size_t)threadIdx.x * 8;
    const float4 a = *(const float4*)(s + i);
    const float4 c = *(const float4*)(s + i + 4);
    ushort8 r;
    r[0] = f2bf(a.x); r[1] = f2bf(a.y); r[2] = f2bf(a.z); r[3] = f2bf(a.w);
    r[4] = f2bf(c.x); r[5] = f2bf(c.y); r[6] = f2bf(c.z); r[7] = f2bf(c.w);
    *(ushort8*)(d + i) = r;
}

// ---------------------------------------------------------------------------
// V (BH,S,DH) -> Vt (BH,DH,S) transpose, bf16, LDS tiled. Tiles wholly past
// ceil32(vlen[b]) skipped.
// ---------------------------------------------------------------------------
__global__ __launch_bounds__(256)
void transpose_v(const u16* __restrict__ Vp, const int* __restrict__ vlens,
                 u16* __restrict__ Vt)
{
    __shared__ __align__(16) u16 tile[64][72];
    const int t = threadIdx.x;
    const int s0 = blockIdx.x * 64;
    const int bh = blockIdx.y;
    const int b  = bh >> 4;
    const int c32 = ((vlens[b] + 31) >> 5) << 5;
    if (s0 >= c32) return;
    const u16* src = Vp + ((size_t)bh * SS + s0) * DHH;
    const int r = t >> 2, d0 = (t & 3) * 16;
    *(ushort8*)&tile[r][d0]     = *(const ushort8*)(src + r * DHH + d0);
    *(ushort8*)&tile[r][d0 + 8] = *(const ushort8*)(src + r * DHH + d0 + 8);
    __syncthreads();
    const int d = t >> 2, sl = (t & 3) * 16;
    ushort8 o0, o1;
    #pragma unroll
    for (int j = 0; j < 8; ++j) o0[j] = tile[sl + j][d];
    #pragma unroll
    for (int j = 0; j < 8; ++j) o1[j] = tile[sl + 8 + j][d];
    u16* dst = Vt + ((size_t)bh * DHH + d) * SS + s0 + sl;
    *(ushort8*)dst       = o0;
    *(ushort8*)(dst + 8) = o1;
}

// ---------------------------------------------------------------------------
// Shared GEMM core: C = A (Mx1024) @ B^T, 128x128 tile, BK=32, m97 structure.
// OUT_MODE 0: fp32 row-major. OUT_MODE 1: bf16 head-split (B,H,S,DH).
// ---------------------------------------------------------------------------
template<int OUT_MODE>
__device__ __forceinline__
void gemm_core(const u16* __restrict__ A, const u16* __restrict__ B,
               void* __restrict__ Cv, int m0, int n0, u16* As, u16* Bs)
{
    const int t = threadIdx.x;
    const int w = t >> 6, l = t & 63;
    const int lm = l & 15, lg = l >> 4;
    const int wr = w >> 1, wc = w & 1;

    const u16* ga = A + (size_t)(m0 + w * 32 + (l >> 2)) * DD + (l & 3) * 8;
    const u16* gb = B + (size_t)(n0 + w * 32 + (l >> 2)) * DD + (l & 3) * 8;
    u16* lA0 = &As[w * 1024];
    u16* lA1 = &As[w * 1024 + 512];
    u16* lB0 = &Bs[w * 1024];
    u16* lB1 = &Bs[w * 1024 + 512];

    f32x4 acc[4][4];
    #pragma unroll
    for (int i = 0; i < 4; ++i)
        #pragma unroll
        for (int j = 0; j < 4; ++j)
            acc[i][j] = (f32x4){0.f, 0.f, 0.f, 0.f};

    for (int k0 = 0; k0 < DD; k0 += 32) {
        __syncthreads();
        gload16(ga + k0,           lA0);
        gload16(ga + k0 + 16 * DD, lA1);
        gload16(gb + k0,           lB0);
        gload16(gb + k0 + 16 * DD, lB1);
        __syncthreads();
        bf16x8 af[4], bfr[4];
        #pragma unroll
        for (int mi = 0; mi < 4; ++mi)
            af[mi] = *(const bf16x8*)&As[(wr * 64 + mi * 16 + lm) * 32 + lg * 8];
        #pragma unroll
        for (int ni = 0; ni < 4; ++ni)
            bfr[ni] = *(const bf16x8*)&Bs[(wc * 64 + ni * 16 + lm) * 32 + lg * 8];
        #pragma unroll
        for (int mi = 0; mi < 4; ++mi)
            #pragma unroll
            for (int ni = 0; ni < 4; ++ni)
                acc[mi][ni] = __builtin_amdgcn_mfma_f32_16x16x32_bf16(
                    af[mi], bfr[ni], acc[mi][ni], 0, 0, 0);
    }

    #pragma unroll
    for (int mi = 0; mi < 4; ++mi) {
        #pragma unroll
        for (int r = 0; r < 4; ++r) {
            const int m = m0 + wr * 64 + mi * 16 + lg * 4 + r;
            if (OUT_MODE == 0) {
                float* C = (float*)Cv;
                #pragma unroll
                for (int ni = 0; ni < 4; ++ni)
                    C[(size_t)m * DD + n0 + wc * 64 + ni * 16 + lm] = acc[mi][ni][r];
            } else {
                u16* C = (u16*)Cv;
                const int b = m >> 11, s = m & (SS - 1);
                #pragma unroll
                for (int ni = 0; ni < 4; ++ni) {
                    const int n = n0 + wc * 64 + ni * 16 + lm;
                    const int h = n >> 6, dh = n & 63;
                    C[(((size_t)b * HH + h) * SS + s) * DHH + dh] = f2bf(acc[mi][ni][r]);
                }
            }
        }
    }
}

// All 3 projections in one launch: z = 0/1/2 -> Q/K/V. K/V blocks wholly past
// ceil32(vlen[b]) early-exit (rows never read unmasked by flash).
__global__ __launch_bounds__(256)
void gemm_qkv(const u16* __restrict__ Xq, const u16* __restrict__ Xk,
              const u16* __restrict__ Xv,
              const u16* __restrict__ Wqb, const u16* __restrict__ Wkb,
              const u16* __restrict__ Wvb,
              u16* __restrict__ Qo, u16* __restrict__ Ko, u16* __restrict__ Vo,
              const int* __restrict__ vlens)
{
    __shared__ __align__(16) u16 As[128 * 32];
    __shared__ __align__(16) u16 Bs[128 * 32];
    const int z = blockIdx.z;
    const int m0 = blockIdx.y * 128, n0 = blockIdx.x * 128;
    const u16* A; const u16* B; u16* C;
    if (z == 0) { A = Xq; B = Wqb; C = Qo; }
    else if (z == 1) { A = Xk; B = Wkb; C = Ko; }
    else { A = Xv; B = Wvb; C = Vo; }
    if (z != 0) {
        const int b = m0 >> 11, s0 = m0 & (SS - 1);
        const int c32 = ((vlens[b] + 31) >> 5) << 5;
        if (s0 >= c32) return;
    }
    gemm_core<1>(A, B, (void*)C, m0, n0, As, Bs);
}

__global__ __launch_bounds__(256)
void gemm_out(const u16* __restrict__ A, const u16* __restrict__ B,
              float* __restrict__ C)
{
    __shared__ __align__(16) u16 As[128 * 32];
    __shared__ __align__(16) u16 Bs[128 * 32];
    gemm_core<0>(A, B, (void*)C, blockIdx.y * 128, blockIdx.x * 128, As, Bs);
}

// ---------------------------------------------------------------------------
// MFMA flash attention v7 = v4 grid (qblk,h,b — proven L2 locality) +
// permlane32_swap softmax + K prefetch depth 2 (ping-pong kfa/kfb).
//   S^T = mfma(A=K, B=Q)     -> lane owns one q-row (q = lane&31) of scores
//   O^T = mfma(A=V^T, B=P^T) -> lane owns one q-row of output
// ---------------------------------------------------------------------------
#define LOADK7(BUF, coff) do {                                                 \
    const u16* kp_ = kb + (size_t)(coff) * DHH;                                \
    BUF[0] = *(const bf16x8*)kp_;                                              \
    BUF[1] = *(const bf16x8*)(kp_ + 16);                                       \
    BUF[2] = *(const bf16x8*)(kp_ + 32);                                       \
    BUF[3] = *(const bf16x8*)(kp_ + 48);                                       \
} while (0)

#define LOADV7(coff) do {                                                      \
    const u16* vp_ = vb + (coff);                                              \
    va[0] = *(const bf16x8*)vp_;                                               \
    va[1] = *(const bf16x8*)(vp_ + 16);                                        \
    va[2] = *(const bf16x8*)(vp_ + (size_t)32 * SS);                           \
    va[3] = *(const bf16x8*)(vp_ + (size_t)32 * SS + 16);                      \
} while (0)

// One KV tile (32 cols) using K-fragment buffer KBUF; prefetches K(tt+2) into
// KBUF (just consumed -> WAR-safe) and V(tt+1) into va after PV.
#define FSTEP(KBUF) do {                                                       \
    const int c0 = tt * 32;                                                    \
    f32x16 z;                                                                  \
    _Pragma("unroll")                                                          \
    for (int r = 0; r < 16; ++r) z[r] = 0.f;                                   \
    __builtin_amdgcn_s_setprio(1);                                             \
    z = __builtin_amdgcn_mfma_f32_32x32x16_bf16(KBUF[0], qv[0], z, 0, 0, 0);   \
    z = __builtin_amdgcn_mfma_f32_32x32x16_bf16(KBUF[1], qv[1], z, 0, 0, 0);   \
    z = __builtin_amdgcn_mfma_f32_32x32x16_bf16(KBUF[2], qv[2], z, 0, 0, 0);   \
    z = __builtin_amdgcn_mfma_f32_32x32x16_bf16(KBUF[3], qv[3], z, 0, 0, 0);   \
    __builtin_amdgcn_s_setprio(0);                                             \
    if (tt + 2 < ntb) LOADK7(KBUF, c0 + 64);                                   \
    if (vlen - c0 < 32) {                                                      \
        _Pragma("unroll")                                                      \
        for (int r = 0; r < 16; ++r) {                                         \
            const int kvl = (r & 3) + 8 * (r >> 2) + 4 * hi;                   \
            if (c0 + kvl >= vlen) z[r] = -3e38f;                               \
        }                                                                      \
    }                                                                          \
    float mx = fmaxf(z[0], z[1]);                                              \
    _Pragma("unroll")                                                          \
    for (int r = 2; r < 16; ++r) mx = fmaxf(mx, z[r]);                         \
    mx = xhalf_max(mx);                                                        \
    float corr = 1.f;                                                          \
    if (!__all(mx <= m_run + 64.0f)) {                                         \
        const float mold = m_run;                                              \
        m_run = fmaxf(m_run, mx);                                              \
        corr = exp2f((mold - m_run) * SC);                                     \
        _Pragma("unroll")                                                      \
        for (int r = 0; r < 16; ++r) { ot0[r] *= corr; ot1[r] *= corr; }       \
    }                                                                          \
    const float msc = m_run * SC;                                              \
    float tsum = 0.f;                                                          \
    _Pragma("unroll")                                                          \
    for (int r = 0; r < 16; ++r) {                                             \
        const float p = exp2f(__builtin_fmaf(z[r], SC, -msc));                 \
        z[r] = p;                                                              \
        tsum += p;                                                             \
    }                                                                          \
    tsum = xhalf_sum(tsum);                                                    \
    l_run = l_run * corr + tsum;                                               \
    unsigned u0, u1, u2, u3, u4, u5, u6, u7;                                   \
    asm("v_cvt_pk_bf16_f32 %0, %1, %2" : "=v"(u0) : "v"(z[0]),  "v"(z[1]));    \
    asm("v_cvt_pk_bf16_f32 %0, %1, %2" : "=v"(u1) : "v"(z[2]),  "v"(z[3]));    \
    asm("v_cvt_pk_bf16_f32 %0, %1, %2" : "=v"(u2) : "v"(z[4]),  "v"(z[5]));    \
    asm("v_cvt_pk_bf16_f32 %0, %1, %2" : "=v"(u3) : "v"(z[6]),  "v"(z[7]));    \
    asm("v_cvt_pk_bf16_f32 %0, %1, %2" : "=v"(u4) : "v"(z[8]),  "v"(z[9]));    \
    asm("v_cvt_pk_bf16_f32 %0, %1, %2" : "=v"(u5) : "v"(z[10]), "v"(z[11]));   \
    asm("v_cvt_pk_bf16_f32 %0, %1, %2" : "=v"(u6) : "v"(z[12]), "v"(z[13]));   \
    asm("v_cvt_pk_bf16_f32 %0, %1, %2" : "=v"(u7) : "v"(z[14]), "v"(z[15]));   \
    plswap(u0, u2);                                                            \
    plswap(u1, u3);                                                            \
    plswap(u4, u6);                                                            \
    plswap(u5, u7);                                                            \
    bf16x8 pb0, pb1;                                                           \
    ((unsigned*)&pb0)[0] = u0; ((unsigned*)&pb0)[1] = u1;                      \
    ((unsigned*)&pb0)[2] = u2; ((unsigned*)&pb0)[3] = u3;                      \
    ((unsigned*)&pb1)[0] = u4; ((unsigned*)&pb1)[1] = u5;                      \
    ((unsigned*)&pb1)[2] = u6; ((unsigned*)&pb1)[3] = u7;                      \
    __builtin_amdgcn_s_setprio(1);                                             \
    ot0 = __builtin_amdgcn_mfma_f32_32x32x16_bf16(va[0], pb0, ot0, 0, 0, 0);   \
    ot0 = __builtin_amdgcn_mfma_f32_32x32x16_bf16(va[1], pb1, ot0, 0, 0, 0);   \
    ot1 = __builtin_amdgcn_mfma_f32_32x32x16_bf16(va[2], pb0, ot1, 0, 0, 0);   \
    ot1 = __builtin_amdgcn_mfma_f32_32x32x16_bf16(va[3], pb1, ot1, 0, 0, 0);   \
    __builtin_amdgcn_s_setprio(0);                                             \
    if (tt + 1 < ntb) LOADV7(c0 + 32);                                         \
} while (0)

__global__ __launch_bounds__(256)
void flash_mfma7(const u16* __restrict__ Qp, const u16* __restrict__ Kp,
                 const u16* __restrict__ Vt, const int* __restrict__ vlens,
                 u16* __restrict__ AO)
{
    const int t = threadIdx.x, w = t >> 6, l = t & 63;
    const int l31 = l & 31, hi = l >> 5;
    const int qblk = blockIdx.x, h = blockIdx.y, b = blockIdx.z;
    const int bh = b * 16 + h;
    const int q0 = (qblk * 4 + w) * 32;
    const int vlen = vlens[b];
    const int ntb = (vlen + 31) >> 5;

    const float SC = 0.18033688011112042f;   // 0.125 * log2(e)

    const u16* qb = Qp + ((size_t)bh * SS + q0 + l31) * DHH + hi * 8;
    bf16x8 qv[4];
    qv[0] = *(const bf16x8*)qb;
    qv[1] = *(const bf16x8*)(qb + 16);
    qv[2] = *(const bf16x8*)(qb + 32);
    qv[3] = *(const bf16x8*)(qb + 48);

    const u16* kb = Kp + ((size_t)bh * SS + l31) * DHH + hi * 8;
    const u16* vb = Vt + ((size_t)bh * DHH + l31) * SS + hi * 8;

    bf16x8 kfa[4], kfb[4], va[4];
    LOADK7(kfa, 0);
    LOADV7(0);
    if (ntb > 1) LOADK7(kfb, 32);

    f32x16 ot0, ot1;
    #pragma unroll
    for (int r = 0; r < 16; ++r) { ot0[r] = 0.f; ot1[r] = 0.f; }
    float m_run = -3e38f, l_run = 0.f;

    int tt = 0;
    for (;;) {
        FSTEP(kfa);
        if (++tt >= ntb) break;
        FSTEP(kfb);
        if (++tt >= ntb) break;
    }

    // --- normalize + write: lane owns q-row q0+l31; d = 32*dh + (r&3)+8(r>>2)+4hi
    const float inv = 1.f / l_run;
    u16* ob = AO + ((size_t)b * SS + q0 + l31) * DD + h * DHH + hi * 4;
    #pragma unroll
    for (int rq = 0; rq < 4; ++rq) {
        #pragma unroll
        for (int rp = 0; rp < 2; ++rp) {
            const int r = rq * 4 + rp * 2;
            unsigned w0, w1;
            asm("v_cvt_pk_bf16_f32 %0, %1, %2" : "=v"(w0)
                : "v"(ot0[r] * inv), "v"(ot0[r + 1] * inv));
            asm("v_cvt_pk_bf16_f32 %0, %1, %2" : "=v"(w1)
                : "v"(ot1[r] * inv), "v"(ot1[r + 1] * inv));
            *(unsigned*)(ob + rq * 8 + rp * 2)      = w0;
            *(unsigned*)(ob + 32 + rq * 8 + rp * 2) = w1;
        }
    }
}

extern "C" void kernel_launch(void* const* d_in, const int* in_sizes, int n_in,
                              void* d_out, int out_size, void* d_ws, size_t ws_size,
                              hipStream_t stream) {
    const float* queries = (const float*)d_in[0];
    const float* keys    = (const float*)d_in[1];
    const float* values  = (const float*)d_in[2];
    const int*   vlens   = (const int*)d_in[3];
    const float* Wq      = (const float*)d_in[4];
    const float* Wk      = (const float*)d_in[5];
    const float* Wv      = (const float*)d_in[6];
    const float* Wo      = (const float*)d_in[7];

    u16* ws = (u16*)d_ws;
    const size_t NX = (size_t)BB * SS * DD;   // 8,388,608
    const size_t NW = (size_t)DD * DD;        // 1,048,576
    u16* Xq  = ws;
    u16* Xk  = Xq  + NX;
    u16* Xv  = Xk  + NX;
    u16* Wqb = Xv  + NX;
    u16* Wkb = Wqb + NW;
    u16* Wvb = Wkb + NW;
    u16* Wob = Wvb + NW;
    u16* Qp  = Wob + NW;
    u16* Kp  = Qp  + NX;
    u16* Vp  = Kp  + NX;
    u16* Vtb = Vp  + NX;
    u16* AO  = Xq;   // alias: Xq dead after the Q projection

    cvt_all<<<dim3(14336), 256, 0, stream>>>(queries, keys, values,
                                             Wq, Wk, Wv, Wo, vlens,
                                             Xq, Xk, Xv, Wqb, Wkb, Wvb, Wob);

    gemm_qkv<<<dim3(DD / 128, (BB * SS) / 128, 3), 256, 0, stream>>>(
        Xq, Xk, Xv, Wqb, Wkb, Wvb, Qp, Kp, Vp, vlens);

    transpose_v<<<dim3(SS / 64, NBH), 256, 0, stream>>>(Vp, vlens, Vtb);
    flash_mfma7<<<dim3(16, HH, BB), 256, 0, stream>>>(Qp, Kp, Vtb, vlens, AO);

    gemm_out<<<dim3(DD / 128, (BB * SS) / 128), 256, 0, stream>>>(AO, Wob, (float*)d_out);
}

// Round 10
// 246.734 us; speedup vs baseline: 1.2867x; 1.1431x over previous
//
#include <hip/hip_runtime.h>
#include <math.h>

#define BB 4
#define SS 2048
#define DD 1024
#define HH 16
#define DHH 64
#define NBH 64

typedef __attribute__((ext_vector_type(8))) short bf16x8;
typedef __attribute__((ext_vector_type(8))) unsigned short ushort8;
typedef __attribute__((ext_vector_type(4))) float f32x4;
typedef __attribute__((ext_vector_type(16))) float f32x16;
typedef __attribute__((ext_vector_type(2))) unsigned u32x2;
typedef unsigned short u16;

__device__ inline u16 f2bf(float x) {
    union { float f; unsigned u; } v; v.f = x;
    unsigned r = v.u + 0x7fffu + ((v.u >> 16) & 1u);   // RNE
    return (u16)(r >> 16);
}

__device__ inline void gload16(const u16* g, u16* l) {
    __builtin_amdgcn_global_load_lds(
        (const __attribute__((address_space(1))) unsigned int*)(const void*)g,
        (__attribute__((address_space(3))) unsigned int*)(void*)l, 16, 0, 0);
}

// SSA-safe cross-half primitives (builtin returns BOTH results — no aliasing).
__device__ inline void plswap(unsigned& a, unsigned& b) {
    u32x2 r = __builtin_amdgcn_permlane32_swap(a, b, false, false);
    a = r[0]; b = r[1];
}
__device__ inline float xhalf_max(float x) {
    u32x2 r = __builtin_amdgcn_permlane32_swap(
        __float_as_uint(x), __float_as_uint(x), false, false);
    return fmaxf(__uint_as_float(r[0]), __uint_as_float(r[1]));
}
__device__ inline float xhalf_sum(float x) {
    u32x2 r = __builtin_amdgcn_permlane32_swap(
        __float_as_uint(x), __float_as_uint(x), false, false);
    return __uint_as_float(r[0]) + __uint_as_float(r[1]);
}

// ---------------------------------------------------------------------------
// fp32 -> bf16 conversion, ALL tensors in one launch.
// blocks [0,12288): q/k/v (4096 each); [12288,14336): weights (512 each).
// K/V rows s >= ceil32(vlen[b]) skipped (never consumed unmasked downstream).
// ---------------------------------------------------------------------------
__global__ __launch_bounds__(256)
void cvt_all(const float* __restrict__ q, const float* __restrict__ k,
             const float* __restrict__ v,
             const float* __restrict__ wq, const float* __restrict__ wk,
             const float* __restrict__ wv, const float* __restrict__ wo,
             const int* __restrict__ vlens,
             u16* __restrict__ oq, u16* __restrict__ ok, u16* __restrict__ ov,
             u16* __restrict__ owq, u16* __restrict__ owk,
             u16* __restrict__ owv, u16* __restrict__ owo)
{
    const int id = blockIdx.x;
    const float* s; u16* d; size_t i0;
    if (id < 12288) {
        const int y = id >> 12, xx = id & 4095;
        i0 = (size_t)xx * 2048;
        if (y == 0) { s = q; d = oq; }
        else if (y == 1) { s = k; d = ok; }
        else { s = v; d = ov; }
        if (y != 0) {
            const int b  = (int)(i0 >> 21);
            const int s0 = (int)(i0 >> 10) & (SS - 1);
            const int c32 = ((vlens[b] + 31) >> 5) << 5;
            if (s0 >= c32) return;
        }
    } else {
        const int r = id - 12288;
        const int y = r >> 9, xx = r & 511;
        i0 = (size_t)xx * 2048;
        if (y == 0) { s = wq; d = owq; }
        else if (y == 1) { s = wk; d = owk; }
        else if (y == 2) { s = wv; d = owv; }
        else { s = wo; d = owo; }
    }
    const size_t i = i0 + (size_t)threadIdx.x * 8;
    const float4 a = *(const float4*)(s + i);
    const float4 c = *(const float4*)(s + i + 4);
    ushort8 r;
    r[0] = f2bf(a.x); r[1] = f2bf(a.y); r[2] = f2bf(a.z); r[3] = f2bf(a.w);
    r[4] = f2bf(c.x); r[5] = f2bf(c.y); r[6] = f2bf(c.z); r[7] = f2bf(c.w);
    *(ushort8*)(d + i) = r;
}

// ---------------------------------------------------------------------------
// V (BH,S,DH) -> Vt (BH,DH,S) transpose, bf16, LDS tiled. Tiles wholly past
// ceil32(vlen[b]) skipped.
// ---------------------------------------------------------------------------
__global__ __launch_bounds__(256)
void transpose_v(const u16* __restrict__ Vp, const int* __restrict__ vlens,
                 u16* __restrict__ Vt)
{
    __shared__ __align__(16) u16 tile[64][72];
    const int t = threadIdx.x;
    const int s0 = blockIdx.x * 64;
    const int bh = blockIdx.y;
    const int b  = bh >> 4;
    const int c32 = ((vlens[b] + 31) >> 5) << 5;
    if (s0 >= c32) return;
    const u16* src = Vp + ((size_t)bh * SS + s0) * DHH;
    const int r = t >> 2, d0 = (t & 3) * 16;
    *(ushort8*)&tile[r][d0]     = *(const ushort8*)(src + r * DHH + d0);
    *(ushort8*)&tile[r][d0 + 8] = *(const ushort8*)(src + r * DHH + d0 + 8);
    __syncthreads();
    const int d = t >> 2, sl = (t & 3) * 16;
    ushort8 o0, o1;
    #pragma unroll
    for (int j = 0; j < 8; ++j) o0[j] = tile[sl + j][d];
    #pragma unroll
    for (int j = 0; j < 8; ++j) o1[j] = tile[sl + 8 + j][d];
    u16* dst = Vt + ((size_t)bh * DHH + d) * SS + s0 + sl;
    *(ushort8*)dst       = o0;
    *(ushort8*)(dst + 8) = o1;
}

// ---------------------------------------------------------------------------
// Shared GEMM core: C = A (Mx1024) @ B^T, 128x128 tile, BK=32, m97 structure.
// OUT_MODE 0: fp32 row-major. OUT_MODE 1: bf16 head-split (B,H,S,DH).
// ---------------------------------------------------------------------------
template<int OUT_MODE>
__device__ __forceinline__
void gemm_core(const u16* __restrict__ A, const u16* __restrict__ B,
               void* __restrict__ Cv, int m0, int n0, u16* As, u16* Bs)
{
    const int t = threadIdx.x;
    const int w = t >> 6, l = t & 63;
    const int lm = l & 15, lg = l >> 4;
    const int wr = w >> 1, wc = w & 1;

    const u16* ga = A + (size_t)(m0 + w * 32 + (l >> 2)) * DD + (l & 3) * 8;
    const u16* gb = B + (size_t)(n0 + w * 32 + (l >> 2)) * DD + (l & 3) * 8;
    u16* lA0 = &As[w * 1024];
    u16* lA1 = &As[w * 1024 + 512];
    u16* lB0 = &Bs[w * 1024];
    u16* lB1 = &Bs[w * 1024 + 512];

    f32x4 acc[4][4];
    #pragma unroll
    for (int i = 0; i < 4; ++i)
        #pragma unroll
        for (int j = 0; j < 4; ++j)
            acc[i][j] = (f32x4){0.f, 0.f, 0.f, 0.f};

    for (int k0 = 0; k0 < DD; k0 += 32) {
        __syncthreads();
        gload16(ga + k0,           lA0);
        gload16(ga + k0 + 16 * DD, lA1);
        gload16(gb + k0,           lB0);
        gload16(gb + k0 + 16 * DD, lB1);
        __syncthreads();
        bf16x8 af[4], bfr[4];
        #pragma unroll
        for (int mi = 0; mi < 4; ++mi)
            af[mi] = *(const bf16x8*)&As[(wr * 64 + mi * 16 + lm) * 32 + lg * 8];
        #pragma unroll
        for (int ni = 0; ni < 4; ++ni)
            bfr[ni] = *(const bf16x8*)&Bs[(wc * 64 + ni * 16 + lm) * 32 + lg * 8];
        #pragma unroll
        for (int mi = 0; mi < 4; ++mi)
            #pragma unroll
            for (int ni = 0; ni < 4; ++ni)
                acc[mi][ni] = __builtin_amdgcn_mfma_f32_16x16x32_bf16(
                    af[mi], bfr[ni], acc[mi][ni], 0, 0, 0);
    }

    #pragma unroll
    for (int mi = 0; mi < 4; ++mi) {
        #pragma unroll
        for (int r = 0; r < 4; ++r) {
            const int m = m0 + wr * 64 + mi * 16 + lg * 4 + r;
            if (OUT_MODE == 0) {
                float* C = (float*)Cv;
                #pragma unroll
                for (int ni = 0; ni < 4; ++ni)
                    C[(size_t)m * DD + n0 + wc * 64 + ni * 16 + lm] = acc[mi][ni][r];
            } else {
                u16* C = (u16*)Cv;
                const int b = m >> 11, s = m & (SS - 1);
                #pragma unroll
                for (int ni = 0; ni < 4; ++ni) {
                    const int n = n0 + wc * 64 + ni * 16 + lm;
                    const int h = n >> 6, dh = n & 63;
                    C[(((size_t)b * HH + h) * SS + s) * DHH + dh] = f2bf(acc[mi][ni][r]);
                }
            }
        }
    }
}

// All 3 projections in one launch: z = 0/1/2 -> Q/K/V. K/V blocks wholly past
// ceil32(vlen[b]) early-exit (rows never read unmasked by flash).
__global__ __launch_bounds__(256)
void gemm_qkv(const u16* __restrict__ Xq, const u16* __restrict__ Xk,
              const u16* __restrict__ Xv,
              const u16* __restrict__ Wqb, const u16* __restrict__ Wkb,
              const u16* __restrict__ Wvb,
              u16* __restrict__ Qo, u16* __restrict__ Ko, u16* __restrict__ Vo,
              const int* __restrict__ vlens)
{
    __shared__ __align__(16) u16 As[128 * 32];
    __shared__ __align__(16) u16 Bs[128 * 32];
    const int z = blockIdx.z;
    const int m0 = blockIdx.y * 128, n0 = blockIdx.x * 128;
    const u16* A; const u16* B; u16* C;
    if (z == 0) { A = Xq; B = Wqb; C = Qo; }
    else if (z == 1) { A = Xk; B = Wkb; C = Ko; }
    else { A = Xv; B = Wvb; C = Vo; }
    if (z != 0) {
        const int b = m0 >> 11, s0 = m0 & (SS - 1);
        const int c32 = ((vlens[b] + 31) >> 5) << 5;
        if (s0 >= c32) return;
    }
    gemm_core<1>(A, B, (void*)C, m0, n0, As, Bs);
}

__global__ __launch_bounds__(256)
void gemm_out(const u16* __restrict__ A, const u16* __restrict__ B,
              float* __restrict__ C)
{
    __shared__ __align__(16) u16 As[128 * 32];
    __shared__ __align__(16) u16 Bs[128 * 32];
    gemm_core<0>(A, B, (void*)C, blockIdx.y * 128, blockIdx.x * 128, As, Bs);
}

// ---------------------------------------------------------------------------
// MFMA flash attention v8 = v4's exact loop structure (depth-1 K/V prefetch,
// single body — proven 142us) + permlane32_swap softmax + XCD-aware swizzle:
// blockIdx.x = ((bh>>3)*16 + qblk)*8 + (bh&7), so all 16 q-blocks of one
// (b,h) share blockIdx mod 8 -> same XCD -> K/V stream is L2-resident after
// first touch (~200cyc loads instead of ~900cyc HBM).
//   S^T = mfma(A=K, B=Q)     -> lane owns one q-row (q = lane&31) of scores
//   O^T = mfma(A=V^T, B=P^T) -> lane owns one q-row of output
// ---------------------------------------------------------------------------
#define LOADK4(coff) do {                                                      \
    const u16* kp_ = kb + (size_t)(coff) * DHH;                                \
    kf[0] = *(const bf16x8*)kp_;                                               \
    kf[1] = *(const bf16x8*)(kp_ + 16);                                        \
    kf[2] = *(const bf16x8*)(kp_ + 32);                                        \
    kf[3] = *(const bf16x8*)(kp_ + 48);                                        \
} while (0)

#define LOADV4(coff) do {                                                      \
    const u16* vp_ = vb + (coff);                                              \
    va[0] = *(const bf16x8*)vp_;                                               \
    va[1] = *(const bf16x8*)(vp_ + 16);                                        \
    va[2] = *(const bf16x8*)(vp_ + (size_t)32 * SS);                           \
    va[3] = *(const bf16x8*)(vp_ + (size_t)32 * SS + 16);                      \
} while (0)

__global__ __launch_bounds__(256)
void flash_mfma8(const u16* __restrict__ Qp, const u16* __restrict__ Kp,
                 const u16* __restrict__ Vt, const int* __restrict__ vlens,
                 u16* __restrict__ AO)
{
    const int t = threadIdx.x, w = t >> 6, l = t & 63;
    const int l31 = l & 31, hi = l >> 5;
    // XCD-aware decode: xcd = x&7 owns bh pairs with bh%8 == xcd.
    const int x = blockIdx.x;
    const int xcd = x & 7;
    const int idx = x >> 3;                 // 0..127
    const int bh  = xcd + ((idx >> 4) << 3);
    const int qblk = idx & 15;
    const int b = bh >> 4, h = bh & 15;
    const int q0 = (qblk * 4 + w) * 32;
    const int vlen = vlens[b];
    const int ntb = (vlen + 31) >> 5;

    const float SC = 0.18033688011112042f;   // 0.125 * log2(e)

    const u16* qb = Qp + ((size_t)bh * SS + q0 + l31) * DHH + hi * 8;
    bf16x8 qv[4];
    qv[0] = *(const bf16x8*)qb;
    qv[1] = *(const bf16x8*)(qb + 16);
    qv[2] = *(const bf16x8*)(qb + 32);
    qv[3] = *(const bf16x8*)(qb + 48);

    const u16* kb = Kp + ((size_t)bh * SS + l31) * DHH + hi * 8;
    const u16* vb = Vt + ((size_t)bh * DHH + l31) * SS + hi * 8;

    bf16x8 kf[4], va[4];
    LOADK4(0);
    LOADV4(0);

    f32x16 ot0, ot1;
    #pragma unroll
    for (int r = 0; r < 16; ++r) { ot0[r] = 0.f; ot1[r] = 0.f; }
    float m_run = -3e38f, l_run = 0.f;

    for (int tt = 0; tt < ntb; ++tt) {
        const int c0 = tt * 32;
        f32x16 z;
        #pragma unroll
        for (int r = 0; r < 16; ++r) z[r] = 0.f;
        __builtin_amdgcn_s_setprio(1);
        z = __builtin_amdgcn_mfma_f32_32x32x16_bf16(kf[0], qv[0], z, 0, 0, 0);
        z = __builtin_amdgcn_mfma_f32_32x32x16_bf16(kf[1], qv[1], z, 0, 0, 0);
        z = __builtin_amdgcn_mfma_f32_32x32x16_bf16(kf[2], qv[2], z, 0, 0, 0);
        z = __builtin_amdgcn_mfma_f32_32x32x16_bf16(kf[3], qv[3], z, 0, 0, 0);
        __builtin_amdgcn_s_setprio(0);
        if (tt + 1 < ntb) LOADK4(c0 + 32);

        if (vlen - c0 < 32) {
            #pragma unroll
            for (int r = 0; r < 16; ++r) {
                const int kvl = (r & 3) + 8 * (r >> 2) + 4 * hi;
                if (c0 + kvl >= vlen) z[r] = -3e38f;
            }
        }

        // --- row max: 15 in-lane fmax + SSA-safe cross-half max
        float mx = fmaxf(z[0], z[1]);
        #pragma unroll
        for (int r = 2; r < 16; ++r) mx = fmaxf(mx, z[r]);
        mx = xhalf_max(mx);

        // --- defer-max: rescale only when raw max grows by > 64 (= 8 nats)
        float corr = 1.f;
        if (!__all(mx <= m_run + 64.0f)) {
            const float mold = m_run;
            m_run = fmaxf(m_run, mx);
            corr = exp2f((mold - m_run) * SC);
            #pragma unroll
            for (int r = 0; r < 16; ++r) { ot0[r] *= corr; ot1[r] *= corr; }
        }

        // --- p = exp2(z*SC - m*SC); in-lane sum + SSA-safe cross-half sum
        const float msc = m_run * SC;
        float tsum = 0.f;
        #pragma unroll
        for (int r = 0; r < 16; ++r) {
            const float p = exp2f(__builtin_fmaf(z[r], SC, -msc));
            z[r] = p;
            tsum += p;
        }
        tsum = xhalf_sum(tsum);
        l_run = l_run * corr + tsum;

        // --- pack P to bf16 pairs
        unsigned u0, u1, u2, u3, u4, u5, u6, u7;
        asm("v_cvt_pk_bf16_f32 %0, %1, %2" : "=v"(u0) : "v"(z[0]),  "v"(z[1]));
        asm("v_cvt_pk_bf16_f32 %0, %1, %2" : "=v"(u1) : "v"(z[2]),  "v"(z[3]));
        asm("v_cvt_pk_bf16_f32 %0, %1, %2" : "=v"(u2) : "v"(z[4]),  "v"(z[5]));
        asm("v_cvt_pk_bf16_f32 %0, %1, %2" : "=v"(u3) : "v"(z[6]),  "v"(z[7]));
        asm("v_cvt_pk_bf16_f32 %0, %1, %2" : "=v"(u4) : "v"(z[8]),  "v"(z[9]));
        asm("v_cvt_pk_bf16_f32 %0, %1, %2" : "=v"(u5) : "v"(z[10]), "v"(z[11]));
        asm("v_cvt_pk_bf16_f32 %0, %1, %2" : "=v"(u6) : "v"(z[12]), "v"(z[13]));
        asm("v_cvt_pk_bf16_f32 %0, %1, %2" : "=v"(u7) : "v"(z[14]), "v"(z[15]));

        // --- cross-half exchange, one permlane32_swap per word pair
        plswap(u0, u2);
        plswap(u1, u3);
        plswap(u4, u6);
        plswap(u5, u7);

        bf16x8 pb0, pb1;
        ((unsigned*)&pb0)[0] = u0; ((unsigned*)&pb0)[1] = u1;
        ((unsigned*)&pb0)[2] = u2; ((unsigned*)&pb0)[3] = u3;
        ((unsigned*)&pb1)[0] = u4; ((unsigned*)&pb1)[1] = u5;
        ((unsigned*)&pb1)[2] = u6; ((unsigned*)&pb1)[3] = u7;

        __builtin_amdgcn_s_setprio(1);
        ot0 = __builtin_amdgcn_mfma_f32_32x32x16_bf16(va[0], pb0, ot0, 0, 0, 0);
        ot0 = __builtin_amdgcn_mfma_f32_32x32x16_bf16(va[1], pb1, ot0, 0, 0, 0);
        ot1 = __builtin_amdgcn_mfma_f32_32x32x16_bf16(va[2], pb0, ot1, 0, 0, 0);
        ot1 = __builtin_amdgcn_mfma_f32_32x32x16_bf16(va[3], pb1, ot1, 0, 0, 0);
        __builtin_amdgcn_s_setprio(0);
        if (tt + 1 < ntb) LOADV4(c0 + 32);
    }

    // --- normalize + write: lane owns q-row q0+l31; d = 32*dh + (r&3)+8(r>>2)+4hi
    const float inv = 1.f / l_run;
    u16* ob = AO + ((size_t)b * SS + q0 + l31) * DD + h * DHH + hi * 4;
    #pragma unroll
    for (int rq = 0; rq < 4; ++rq) {
        #pragma unroll
        for (int rp = 0; rp < 2; ++rp) {
            const int r = rq * 4 + rp * 2;
            unsigned w0, w1;
            asm("v_cvt_pk_bf16_f32 %0, %1, %2" : "=v"(w0)
                : "v"(ot0[r] * inv), "v"(ot0[r + 1] * inv));
            asm("v_cvt_pk_bf16_f32 %0, %1, %2" : "=v"(w1)
                : "v"(ot1[r] * inv), "v"(ot1[r + 1] * inv));
            *(unsigned*)(ob + rq * 8 + rp * 2)      = w0;
            *(unsigned*)(ob + 32 + rq * 8 + rp * 2) = w1;
        }
    }
}

extern "C" void kernel_launch(void* const* d_in, const int* in_sizes, int n_in,
                              void* d_out, int out_size, void* d_ws, size_t ws_size,
                              hipStream_t stream) {
    const float* queries = (const float*)d_in[0];
    const float* keys    = (const float*)d_in[1];
    const float* values  = (const float*)d_in[2];
    const int*   vlens   = (const int*)d_in[3];
    const float* Wq      = (const float*)d_in[4];
    const float* Wk      = (const float*)d_in[5];
    const float* Wv      = (const float*)d_in[6];
    const float* Wo      = (const float*)d_in[7];

    u16* ws = (u16*)d_ws;
    const size_t NX = (size_t)BB * SS * DD;   // 8,388,608
    const size_t NW = (size_t)DD * DD;        // 1,048,576
    u16* Xq  = ws;
    u16* Xk  = Xq  + NX;
    u16* Xv  = Xk  + NX;
    u16* Wqb = Xv  + NX;
    u16* Wkb = Wqb + NW;
    u16* Wvb = Wkb + NW;
    u16* Wob = Wvb + NW;
    u16* Qp  = Wob + NW;
    u16* Kp  = Qp  + NX;
    u16* Vp  = Kp  + NX;
    u16* Vtb = Vp  + NX;
    u16* AO  = Xq;   // alias: Xq dead after the Q projection

    cvt_all<<<dim3(14336), 256, 0, stream>>>(queries, keys, values,
                                             Wq, Wk, Wv, Wo, vlens,
                                             Xq, Xk, Xv, Wqb, Wkb, Wvb, Wob);

    gemm_qkv<<<dim3(DD / 128, (BB * SS) / 128, 3), 256, 0, stream>>>(
        Xq, Xk, Xv, Wqb, Wkb, Wvb, Qp, Kp, Vp, vlens);

    transpose_v<<<dim3(SS / 64, NBH), 256, 0, stream>>>(Vp, vlens, Vtb);
    flash_mfma8<<<dim3(1024), 256, 0, stream>>>(Qp, Kp, Vtb, vlens, AO);

    gemm_out<<<dim3(DD / 128, (BB * SS) / 128), 256, 0, stream>>>(AO, Wob, (float*)d_out);
}